// Round 3
// baseline (1624.262 us; speedup 1.0000x reference)
//
#include <hip/hip_runtime.h>

// HyenaSE gated causal depthwise conv, fp32.
// B=2, D=4096, L=4096, G=256, HL=128.
// out[b,d,t] = q[b,d,t] * sum_{j=0..127} h[d%G, j] * (k*x)[b,d, t-127+j]
//
// R2: block-per-row, LDS kx + rolling register window (154 us, VALUBusy 47%).
// R3 (FAILED): reg-held cross-row prefetch -> scratch spills.
// R4 (FAILED): async global_load_lds pipeline, 12 waves/CU -> 167 us.
//     Post-mortem: nothing saturated (VALU 5.1us/round, mem-at-copy-rate
//     7.8us/round, measured period 15.2us). Grid-wide convoy: barriers +
//     identical per-block code keep all blocks phase-locked; memory and
//     VALU take turns idling, and 12 waves/CU can't fill the gaps.
// R5: BARRIER-FREE wave-independent slices. Each wave owns a 1024-output
//     slice of a row with a private swizzled LDS buffer (pad128+1024).
//     Stage (VGPR loads, x*k, ds_write) -> lgkmcnt(0) -> compute. No
//     s_barrier anywhere; waves drift freely so memory always has demand
//     and SIMDs always have ready FMAs. 32 waves/CU target (VGPR<=64,
//     LDS 18.4KB/block). Halo = 12.5% extra x,k reads, same-CU L1 hits
//     (the 4 slices of a row are the 4 waves of one block).

#define HSE_B  2
#define HSE_D  4096
#define HSE_L  4096
#define HSE_G  256
#define HSE_HL 128

constexpr int TPB   = 256;           // 4 waves per block
constexpr int SLICE = 1024;          // outputs per wave
constexpr int VPT   = 16;            // outputs per thread (64*16 = 1024)
constexpr int PAD   = 128;           // causal window history
constexpr int WBUF  = PAD + SLICE;   // 1152 floats = 4608 B per wave
constexpr int GRID  = (HSE_B * HSE_D * (HSE_L / SLICE)) / 4;  // 8192 blocks

// XOR swizzle on float index: permutes bank-quads (bits 2..4) with bits
// 5..7. 256-float periodic; wave buffer offsets (1152 floats) are 32-float
// multiples so the bank pattern is translation-invariant. Makes the
// stride-16-float window reads conflict-free; preserves float4 alignment.
__device__ __forceinline__ int swiz(int i) {
    return i ^ (((i >> 5) & 7) << 2);
}

__global__ __launch_bounds__(TPB, 8) void hyena_se_kernel(
    const float* __restrict__ x, const float* __restrict__ k,
    const float* __restrict__ q, const float* __restrict__ h,
    float* __restrict__ out)
{
    __shared__ __align__(128) float sbuf[4 * WBUF];   // 18432 B

    const int tid  = threadIdx.x;
    const int lane = tid & 63;
    const int wid  = tid >> 6;

    const int sid  = blockIdx.x * 4 + wid;   // global slice id
    const int row  = sid >> 2;               // (b*D + d)
    const int part = sid & 3;                // slice within row
    const int p0   = part * SLICE;           // first output of this slice
    const size_t rbase = (size_t)row * HSE_L;
    const int d = row & (HSE_D - 1);
    const float* __restrict__ hrow = h + (size_t)(d & (HSE_G - 1)) * HSE_HL;

    float* __restrict__ wb = sbuf + wid * WBUF;   // wave-private buffer

    // --- stage kx for [p0-128, p0+1024) into swizzled wave buffer ---
    // 288 quads: rounds 0..3 all lanes, round 4 lanes 0..31.
    #pragma unroll
    for (int c = 0; c < 5; ++c) {
        if (c < 4 || lane < 32) {
            const int qi   = c * 64 + lane;      // quad index in [0,288)
            const int gpos = p0 - PAD + 4 * qi;  // global row position
            float4 pr = make_float4(0.f, 0.f, 0.f, 0.f);
            if (gpos >= 0) {                     // only part==0, c==0, lane<32 is out
                float4 xv = *(const float4*)(x + rbase + gpos);
                float4 kv = *(const float4*)(k + rbase + gpos);
                pr = make_float4(xv.x * kv.x, xv.y * kv.y,
                                 xv.z * kv.z, xv.w * kv.w);
            }
            ((float4*)wb)[swiz(4 * qi) >> 2] = pr;
        }
    }

    // Wave-private buffer: writes->reads ordered by lgkmcnt alone. NO barrier.
    asm volatile("s_waitcnt lgkmcnt(0)" ::: "memory");
    __builtin_amdgcn_sched_barrier(0);

    // --- compute: rolling register window (unchanged R2 inner loop) ---
    const int t0 = lane * VPT;   // local output base within slice

    float acc[VPT];
    #pragma unroll
    for (int v = 0; v < VPT; ++v) acc[v] = 0.f;

    float w[24];
    #pragma unroll
    for (int m = 0; m < 4; ++m) {
        float4 wv = ((const float4*)wb)[swiz(t0 + 4 * m) >> 2];
        w[4*m+0] = wv.x; w[4*m+1] = wv.y; w[4*m+2] = wv.z; w[4*m+3] = wv.w;
    }

    #pragma unroll
    for (int jc = 0; jc < HSE_HL / 8; ++jc) {
        // 8 new window floats (2 conflict-free b128 reads)
        #pragma unroll
        for (int m = 0; m < 2; ++m) {
            float4 wv = ((const float4*)wb)[swiz(t0 + 8 * jc + 16 + 4 * m) >> 2];
            w[16 + 4*m + 0] = wv.x; w[16 + 4*m + 1] = wv.y;
            w[16 + 4*m + 2] = wv.z; w[16 + 4*m + 3] = wv.w;
        }
        // 8 filter taps from scalar cache (wave-uniform address)
        float hf[8];
        #pragma unroll
        for (int u = 0; u < 8; ++u) hf[u] = hrow[8 * jc + u];

        #pragma unroll
        for (int v = 0; v < VPT; ++v) {
            #pragma unroll
            for (int u = 0; u < 8; ++u) {
                acc[v] = fmaf(hf[u], w[1 + v + u], acc[v]);
            }
        }
        // slide window by 8 (register renaming after full unroll)
        #pragma unroll
        for (int p = 0; p < 16; ++p) w[p] = w[p + 8];
    }

    // --- epilogue: out = q * acc. q loaded here (not prefetched) to keep
    //     the live set through compute <= 64 VGPR; 8 waves/SIMD hide the
    //     latency of these 4 loads. ---
    const size_t obase = rbase + p0 + t0;
    #pragma unroll
    for (int m = 0; m < VPT / 4; ++m) {
        float4 qv = *(const float4*)(q + obase + 4 * m);
        float4 o;
        o.x = qv.x * acc[4*m + 0];
        o.y = qv.y * acc[4*m + 1];
        o.z = qv.z * acc[4*m + 2];
        o.w = qv.w * acc[4*m + 3];
        *(float4*)(out + obase + 4 * m) = o;
    }
}

extern "C" void kernel_launch(void* const* d_in, const int* in_sizes, int n_in,
                              void* d_out, int out_size, void* d_ws, size_t ws_size,
                              hipStream_t stream) {
    const float* x = (const float*)d_in[0];
    const float* k = (const float*)d_in[1];
    const float* q = (const float*)d_in[2];
    const float* h = (const float*)d_in[3];
    float* o = (float*)d_out;

    dim3 grid(GRID);
    dim3 block(TPB);
    hyena_se_kernel<<<grid, block, 0, stream>>>(x, k, q, h, o);
}